// Round 7
// baseline (383.195 us; speedup 1.0000x reference)
//
#include <hip/hip_runtime.h>

#define B_TOT 4096
#define T_LEN 512
#define DIN   8
#define H_DIM 50

// Interleaved hi/lo layout (from R6): one K=128 bf16 row per batch.
//   k' = 2j -> hi of value j, k' = 2j+1 -> lo   (j: 0..49 h, 50..57 x, 58..63 pad)
// Row stride 136 ushorts (272 B). Four buffers: 2 groups x double-buffer.
#define ROWS_U 136            // ushorts per row
#define ROW_UI 68             // uints per row
#define REG_US 2176           // ushorts per buffer (16 rows)
#define REG_UI 1088           // uints per buffer

typedef __attribute__((ext_vector_type(8))) short  short8;   // 8 bf16
typedef __attribute__((ext_vector_type(4))) float  floatx4;  // MFMA acc

__device__ __forceinline__ ushort f2bf_rne(float f) {
  uint u = __float_as_uint(f);
  u += 0x7FFFu + ((u >> 16) & 1u);
  return (ushort)(u >> 16);
}
__device__ __forceinline__ ushort f2bf_trunc(float f) {
  return (ushort)(__float_as_uint(f) >> 16);
}
__device__ __forceinline__ float bf2f(ushort b) {
  return __uint_as_float(((uint)b) << 16);
}
__device__ __forceinline__ float fast_tanh(float v) {
  // tanh(v) = 1 - 2/(1+e^{2v}); abs err ~1e-7
  float e = __expf(2.0f * v);
  return 1.0f - 2.0f * __builtin_amdgcn_rcpf(1.0f + e);
}

// ---------------------------------------------------------------------------
// Latency-hiding via in-block batch-group interleave.
// Measured wall: 4-wave/16-batch designs all stall at ~1100-1170 cy/step with
// issue only ~350-450 cy -> ~700 cy exposed dependency latency (ds_read ->
// MFMA -> tanh -> write -> barrier), 1 wave/SIMD, nothing to overlap.
// Fix: TWO independent 16-batch recurrence groups per block (32 batches,
// 128 blocks). Same waves, same shared W fragments; each barrier interval
// holds both groups' independent chains, so group B's issue fills group A's
// stalls. One __syncthreads per step covers both groups.
// ---------------------------------------------------------------------------
__global__ __launch_bounds__(256, 1) void rnn_fused(
    const float* __restrict__ x, const float* __restrict__ W_ih,
    const float* __restrict__ W_hh, const float* __restrict__ b_ih,
    const float* __restrict__ b_hh, const float* __restrict__ fc_W,
    const float* __restrict__ fc_b, float* __restrict__ out)
{
  // buffers (uint offsets): A0=0, A1=REG_UI, B0=2*REG_UI, B1=3*REG_UI
  __shared__ __align__(16) ushort lds[4 * REG_US];
  uint* const lds32 = (uint*)lds;

  const int tid  = threadIdx.x;
  const int lane = tid & 63;
  const int wave = tid >> 6;      // 0..3 -> n-tile
  const int col  = lane & 15;     // MFMA n-within-tile (and A-row m)
  const int kg   = lane >> 4;     // 0..3 k-group
  const int b0   = blockIdx.x * 32;   // 32 batches: A = b0..b0+15, B = +16..+31

  // ---- B fragments, two interleave orders, in VGPRs (shared by A and B) ---
  const int nG = wave * 16 + col;
  const bool live = (nG < H_DIM);
  union U8 { ushort u[8]; short8 v; };
  short8 Bs[4], Bw[4];
#pragma unroll
  for (int c = 0; c < 4; ++c) {
    U8 bs, bw;
#pragma unroll
    for (int j2 = 0; j2 < 4; ++j2) {
      const int p = c * 16 + kg * 4 + j2;   // value index 0..63
      float w = 0.f;
      if (live) {
        if (p < H_DIM)            w = W_hh[nG * H_DIM + p];
        else if (p < H_DIM + DIN) w = W_ih[nG * DIN + (p - H_DIM)];
      }
      ushort hi = f2bf_rne(w);
      ushort lo = f2bf_trunc(w - bf2f(hi));
      bs.u[2 * j2]     = hi;  bs.u[2 * j2 + 1] = lo;
      bw.u[2 * j2]     = lo;  bw.u[2 * j2 + 1] = hi;
    }
    Bs[c] = bs.v;
    Bw[c] = bw.v;
  }
  const float bv = live ? (b_ih[nG] + b_hh[nG]) : 0.f;
  const floatx4 biasf = {bv, bv, bv, bv};
  const floatx4 zf    = {0.f, 0.f, 0.f, 0.f};

  // ---- zero all 4 buffers (h0 = 0, pads = 0) ------------------------------
  for (int z = tid; z < 4 * REG_UI; z += 256) lds32[z] = 0;
  __syncthreads();

  // ---- x staging: all 256 threads, 1 packed b32 each per step -------------
  const int xrow = tid >> 3;                // 0..31 (A rows 0..15, B rows 16..31)
  const int xd   = tid & 7;                 // d 0..7
  const int xoff = (xrow < 16 ? 0 * REG_UI + xrow * ROW_UI
                              : 2 * REG_UI + (xrow - 16) * ROW_UI) + H_DIM + xd;
  const float* xp = x + ((size_t)(b0 + xrow) * T_LEN) * DIN + xd;
  float px1, px2, px3;
  {
    float x0 = xp[0];
    ushort hi = f2bf_rne(x0);
    ushort lo = f2bf_trunc(x0 - bf2f(hi));
    lds32[xoff] = (uint)hi | ((uint)lo << 16);   // x for t=0 into A0/B0
    px1 = xp[8]; px2 = xp[16]; px3 = xp[24];     // prefetch t=1,2,3
  }
  __syncthreads();

  // xoff is relative to parity-0 buffer; parity-1 buffer is +REG_UI.
  // ---- main recurrence: both groups per barrier interval ------------------
  auto step = [&](int t, int pUS, int qUI) {
    // pUS: ushort offset of parity-p buffers (0 or REG_US)
    // qUI: uint   offset of parity-q buffers (REG_UI or 0)
    const int rb = col * ROWS_U + kg * 8;
    const ushort* lpA = lds + pUS + rb;
    const ushort* lpB = lds + pUS + 2 * REG_US + rb;
    short8 A0 = *(const short8*)(lpA);
    short8 A1 = *(const short8*)(lpA + 32);
    short8 A2 = *(const short8*)(lpA + 64);
    short8 A3 = *(const short8*)(lpA + 96);
    short8 B0 = *(const short8*)(lpB);
    short8 B1 = *(const short8*)(lpB + 32);
    short8 B2 = *(const short8*)(lpB + 64);
    short8 B3 = *(const short8*)(lpB + 96);

    // group A: exact (hiA+loA)(hiW+loW) via two B orders
    floatx4 a0 = biasf, a1 = zf, a2 = zf, a3 = zf;
    a0 = __builtin_amdgcn_mfma_f32_16x16x32_bf16(A0, Bs[0], a0, 0, 0, 0);
    a1 = __builtin_amdgcn_mfma_f32_16x16x32_bf16(A0, Bw[0], a1, 0, 0, 0);
    a2 = __builtin_amdgcn_mfma_f32_16x16x32_bf16(A2, Bs[2], a2, 0, 0, 0);
    a3 = __builtin_amdgcn_mfma_f32_16x16x32_bf16(A2, Bw[2], a3, 0, 0, 0);
    a0 = __builtin_amdgcn_mfma_f32_16x16x32_bf16(A1, Bs[1], a0, 0, 0, 0);
    a1 = __builtin_amdgcn_mfma_f32_16x16x32_bf16(A1, Bw[1], a1, 0, 0, 0);
    a2 = __builtin_amdgcn_mfma_f32_16x16x32_bf16(A3, Bs[3], a2, 0, 0, 0);
    a3 = __builtin_amdgcn_mfma_f32_16x16x32_bf16(A3, Bw[3], a3, 0, 0, 0);
    // group B
    floatx4 c0 = biasf, c1 = zf, c2 = zf, c3 = zf;
    c0 = __builtin_amdgcn_mfma_f32_16x16x32_bf16(B0, Bs[0], c0, 0, 0, 0);
    c1 = __builtin_amdgcn_mfma_f32_16x16x32_bf16(B0, Bw[0], c1, 0, 0, 0);
    c2 = __builtin_amdgcn_mfma_f32_16x16x32_bf16(B2, Bs[2], c2, 0, 0, 0);
    c3 = __builtin_amdgcn_mfma_f32_16x16x32_bf16(B2, Bw[2], c3, 0, 0, 0);
    c0 = __builtin_amdgcn_mfma_f32_16x16x32_bf16(B1, Bs[1], c0, 0, 0, 0);
    c1 = __builtin_amdgcn_mfma_f32_16x16x32_bf16(B1, Bw[1], c1, 0, 0, 0);
    c2 = __builtin_amdgcn_mfma_f32_16x16x32_bf16(B3, Bs[3], c2, 0, 0, 0);
    c3 = __builtin_amdgcn_mfma_f32_16x16x32_bf16(B3, Bw[3], c3, 0, 0, 0);

    floatx4 vA = (a0 + a1) + (a2 + a3);
    floatx4 vB = (c0 + c1) + (c2 + c3);

    // epilogues: tanh + packed hi|lo b32 store (C layout: m=kg*4+r, n=nG)
    if (live) {
      uint* qA = lds32 + qUI;
      uint* qB = lds32 + qUI + 2 * REG_UI;
#pragma unroll
      for (int r = 0; r < 4; ++r) {
        float thA = fast_tanh(vA[r]);
        float thB = fast_tanh(vB[r]);
        ushort hA = f2bf_rne(thA), lA = f2bf_trunc(thA - bf2f(hA));
        ushort hB = f2bf_rne(thB), lB = f2bf_trunc(thB - bf2f(hB));
        const int row = (kg * 4 + r) * ROW_UI + nG;
        qA[row] = (uint)hA | ((uint)lA << 16);
        qB[row] = (uint)hB | ((uint)lB << 16);
      }
    }
    // stage x_{t+1} into parity-q buffer; rotate depth-3 prefetch
    {
      ushort hi = f2bf_rne(px1);
      ushort lo = f2bf_trunc(px1 - bf2f(hi));
      lds32[qUI + xoff] = (uint)hi | ((uint)lo << 16);
      px1 = px2; px2 = px3;
      int tn = t + 4; if (tn > T_LEN - 1) tn = T_LEN - 1;
      px3 = xp[(size_t)tn * DIN];
    }
    __syncthreads();
  };

  for (int t = 0; t < T_LEN; t += 2) {
    step(t,     0,      REG_UI);   // parity0 -> parity1
    step(t + 1, REG_US, 0);        // parity1 -> parity0
  }
  // final h in parity-0 buffers (A0, B0)

  // ---- fc readout: 4 lanes per batch, 32 batches = 128 threads ------------
  if (tid < 128) {
    int m = tid >> 2, kq = tid & 3;    // m 0..31
    const uint* hrow = lds32 + (m < 16 ? m * ROW_UI
                                       : 2 * REG_UI + (m - 16) * ROW_UI);
    float accr = 0.f;
    for (int k = kq; k < H_DIM; k += 4) {
      uint pk = hrow[k];
      float hv = bf2f((ushort)(pk & 0xFFFFu)) + bf2f((ushort)(pk >> 16));
      accr += hv * fc_W[k];
    }
    accr += __shfl_xor(accr, 1);
    accr += __shfl_xor(accr, 2);
    if (kq == 0) out[b0 + m] = accr + fc_b[0];
  }
}

extern "C" void kernel_launch(void* const* d_in, const int* in_sizes, int n_in,
                              void* d_out, int out_size, void* d_ws, size_t ws_size,
                              hipStream_t stream) {
  const float* x    = (const float*)d_in[0];
  const float* W_ih = (const float*)d_in[1];
  const float* W_hh = (const float*)d_in[2];
  const float* b_ih = (const float*)d_in[3];
  const float* b_hh = (const float*)d_in[4];
  const float* fc_W = (const float*)d_in[5];
  const float* fc_b = (const float*)d_in[6];
  rnn_fused<<<dim3(B_TOT / 32), dim3(256), 0, stream>>>(
      x, W_ih, W_hh, b_ih, b_hh, fc_W, fc_b, (float*)d_out);
}